// Round 1
// baseline (2004.879 us; speedup 1.0000x reference)
//
#include <hip/hip_runtime.h>

static constexpr int GRAPHS = 64;
static constexpr int SLOTS = GRAPHS * 6;   // 384 stress accumulators

// force[i] = -pos_grad[i], vectorized
__global__ void init_force_kernel(const float4* __restrict__ pg4,
                                  float4* __restrict__ f4, int n4,
                                  const float* __restrict__ pg,
                                  float* __restrict__ f, int n) {
    int i = blockIdx.x * blockDim.x + threadIdx.x;
    int stride = gridDim.x * blockDim.x;
    for (int k = i; k < n4; k += stride) {
        float4 v = pg4[k];
        f4[k] = make_float4(-v.x, -v.y, -v.z, -v.w);
    }
    // scalar tail
    for (int k = n4 * 4 + i; k < n; k += stride) f[k] = -pg[k];
}

__global__ __launch_bounds__(256) void edge_kernel(
    const float* __restrict__ rij, const float* __restrict__ fij,
    const int* __restrict__ idx0, const int* __restrict__ idx1,
    const int* __restrict__ batch,
    float* __restrict__ force, float* __restrict__ partials, int E) {
    __shared__ float s_acc[SLOTS];
    for (int t = threadIdx.x; t < SLOTS; t += blockDim.x) s_acc[t] = 0.0f;
    __syncthreads();

    const float4* rij4 = (const float4*)rij;
    const float4* fij4 = (const float4*)fij;
    const int4* i04 = (const int4*)idx0;
    const int4* i14 = (const int4*)idx1;

    const int NG = E >> 2;                 // groups of 4 edges
    const int stride = gridDim.x * blockDim.x;
    const int tid0 = blockIdx.x * blockDim.x + threadIdx.x;

    for (int k = tid0; k < NG; k += stride) {
        float4 ra = rij4[3 * k], rb = rij4[3 * k + 1], rc = rij4[3 * k + 2];
        float4 fa = fij4[3 * k], fb = fij4[3 * k + 1], fc = fij4[3 * k + 2];
        int4 i0 = i04[k], i1 = i14[k];

        float rx[4] = {ra.x, ra.w, rb.z, rc.y};
        float ry[4] = {ra.y, rb.x, rb.w, rc.z};
        float rz[4] = {ra.z, rb.y, rc.x, rc.w};
        float fx[4] = {fa.x, fa.w, fb.z, fc.y};
        float fy[4] = {fa.y, fb.x, fb.w, fc.z};
        float fz[4] = {fa.z, fb.y, fc.x, fc.w};
        int s[4] = {i0.x, i0.y, i0.z, i0.w};
        int r[4] = {i1.x, i1.y, i1.z, i1.w};

#pragma unroll
        for (int e = 0; e < 4; ++e) {
            // force scatter
            atomicAdd(&force[3 * s[e] + 0], fx[e]);
            atomicAdd(&force[3 * s[e] + 1], fy[e]);
            atomicAdd(&force[3 * s[e] + 2], fz[e]);
            atomicAdd(&force[3 * r[e] + 0], -fx[e]);
            atomicAdd(&force[3 * r[e] + 1], -fy[e]);
            atomicAdd(&force[3 * r[e] + 2], -fz[e]);
            // virial into graph of receiver node
            int g = batch[r[e]];
            float* a = &s_acc[6 * g];
            atomicAdd(&a[0], rx[e] * fx[e]);
            atomicAdd(&a[1], ry[e] * fy[e]);
            atomicAdd(&a[2], rz[e] * fz[e]);
            atomicAdd(&a[3], rx[e] * fy[e]);
            atomicAdd(&a[4], ry[e] * fz[e]);
            atomicAdd(&a[5], rz[e] * fx[e]);
        }
    }
    // scalar tail edges (E % 4), normally empty
    for (int e = NG * 4 + tid0; e < E; e += stride) {
        float ex = rij[3 * e], ey = rij[3 * e + 1], ez = rij[3 * e + 2];
        float gx = fij[3 * e], gy = fij[3 * e + 1], gz = fij[3 * e + 2];
        int si = idx0[e], ri = idx1[e];
        atomicAdd(&force[3 * si + 0], gx);
        atomicAdd(&force[3 * si + 1], gy);
        atomicAdd(&force[3 * si + 2], gz);
        atomicAdd(&force[3 * ri + 0], -gx);
        atomicAdd(&force[3 * ri + 1], -gy);
        atomicAdd(&force[3 * ri + 2], -gz);
        int g = batch[ri];
        float* a = &s_acc[6 * g];
        atomicAdd(&a[0], ex * gx);
        atomicAdd(&a[1], ey * gy);
        atomicAdd(&a[2], ez * gz);
        atomicAdd(&a[3], ex * gy);
        atomicAdd(&a[4], ey * gz);
        atomicAdd(&a[5], ez * gx);
    }

    __syncthreads();
    // per-block partials, no global atomics
    for (int t = threadIdx.x; t < SLOTS; t += blockDim.x)
        partials[(size_t)blockIdx.x * SLOTS + t] = s_acc[t];
}

__global__ void reduce_finalize_kernel(const float* __restrict__ partials, int nblocks,
                                       const float* __restrict__ cell_grad,
                                       const float* __restrict__ les_cell,
                                       const float* __restrict__ vol,
                                       float* __restrict__ stress_out) {
    int t = blockIdx.x * blockDim.x + threadIdx.x;
    if (t >= SLOTS) return;
    float s = 0.0f;
    for (int b = 0; b < nblocks; ++b) s += partials[(size_t)b * SLOTS + t];
    int g = t / 6, c = t - 6 * g;
    const int va[6] = {0, 1, 2, 0, 1, 0};
    const int vb[6] = {0, 1, 2, 1, 2, 2};
    int a = va[c], bb = vb[c];
    const float* L = les_cell + 9 * g;   // row-major [3][3]
    const float* G = cell_grad + 9 * g;
    // (L^T G)[a][bb] = sum_k L[k][a] * G[k][bb]
    float lr = L[a] * G[bb] + L[3 + a] * G[3 + bb] + L[6 + a] * G[6 + bb];
    stress_out[t] = (-s - lr) / vol[g];
}

extern "C" void kernel_launch(void* const* d_in, const int* in_sizes, int n_in,
                              void* d_out, int out_size, void* d_ws, size_t ws_size,
                              hipStream_t stream) {
    const float* rij = (const float*)d_in[0];
    const float* fij = (const float*)d_in[1];
    const float* pos_grad = (const float*)d_in[2];
    const float* cell_grad = (const float*)d_in[3];
    const float* les_cell = (const float*)d_in[4];
    const float* vol = (const float*)d_in[5];
    const int* edge_idx = (const int*)d_in[6];
    const int* batch = (const int*)d_in[7];

    const int E = in_sizes[0] / 3;
    const int N = in_sizes[2] / 3;

    float* force = (float*)d_out;
    float* stress = (float*)d_out + (size_t)N * 3;
    float* partials = (float*)d_ws;

    int eblocks = 512;
    size_t need = (size_t)eblocks * SLOTS * sizeof(float);
    if (need > ws_size) {
        int fit = (int)(ws_size / (SLOTS * sizeof(float)));
        eblocks = fit > 0 ? fit : 1;
    }

    // 1) force = -pos_grad
    {
        int n = N * 3, n4 = n / 4;
        int blocks = (n4 + 255) / 256;
        if (blocks > 1024) blocks = 1024;
        if (blocks < 1) blocks = 1;
        init_force_kernel<<<blocks, 256, 0, stream>>>(
            (const float4*)pos_grad, (float4*)force, n4, pos_grad, force, n);
    }

    // 2) edge scatter (force atomics + per-block stress partials)
    edge_kernel<<<eblocks, 256, 0, stream>>>(rij, fij, edge_idx, edge_idx + E,
                                             batch, force, partials, E);

    // 3) reduce partials + Ewald cell term
    reduce_finalize_kernel<<<6, 64, 0, stream>>>(partials, eblocks, cell_grad,
                                                 les_cell, vol, stress);
}